// Round 2
// baseline (234.918 us; speedup 1.0000x reference)
//
#include <hip/hip_runtime.h>

#define NMOL 128
#define ZMAX 90
#define BLOCK 256

__device__ __forceinline__ float fast_exp2(float x) {
#if __has_builtin(__builtin_amdgcn_exp2f)
    return __builtin_amdgcn_exp2f(x);
#else
    return exp2f(x);
#endif
}
__device__ __forceinline__ float fast_log2(float x) {
#if __has_builtin(__builtin_amdgcn_logf)
    return __builtin_amdgcn_logf(x);   // v_log_f32 computes log2(x)
#else
    return log2f(x);
#endif
}
__device__ __forceinline__ float fast_rcp(float x) {
#if __has_builtin(__builtin_amdgcn_rcpf)
    return __builtin_amdgcn_rcpf(x);
#else
    return 1.0f / x;
#endif
}

// Pack per-atom data into one 16B struct so the edge kernel does 2 gathers
// instead of 9: {q, ns, Z | is_film<<16, mol}. Also zero-init d_out (harness
// re-poisons it with 0xAA before every timed launch).
__global__ void pack_atoms_kernel(const float* __restrict__ q,
                                  const int* __restrict__ Z,
                                  const float* __restrict__ ns,
                                  const int* __restrict__ idx_m,
                                  const int* __restrict__ is_film,
                                  float4* __restrict__ atoms,
                                  float* __restrict__ out, int nA) {
    int t = blockIdx.x * BLOCK + threadIdx.x;
    if (blockIdx.x == 0 && threadIdx.x < NMOL) out[threadIdx.x] = 0.0f;
    if (t < nA) {
        float4 a;
        a.x = q[t];
        a.y = ns[t];
        a.z = __int_as_float(Z[t] | (is_film[t] << 16));
        a.w = __int_as_float(idx_m[t]);
        atoms[t] = a;
    }
}

// Per-edge math. Returns the (already cutoff-masked) potential; writes mol.
__device__ __forceinline__ float edge_pot(const float4* __restrict__ atoms,
                                          const float* __restrict__ r0_table,
                                          int i, int j,
                                          float x, float y, float z,
                                          int& mol) {
    constexpr float LOG2_CUT = 2.321928094887362f; // log2(5.0)
    const float4 ai = atoms[i];
    const float4 aj = atoms[j];
    const float d2 = fmaf(x, x, fmaf(y, y, z * z));

    int zi = __float_as_int(ai.z);
    int zj = __float_as_int(aj.z);
    const int fi = zi >> 16, fj = zj >> 16;
    zi &= 0xFFFF; zj &= 0xFFFF;
    const float r0 = r0_table[((fi * 2 + fj) * ZMAX + zi) * ZMAX + zj];

    const float qij = fabsf(ai.x * aj.x);
    const float n = fmaf(0.5f, aj.y, ai.y);              // ns_i + ns_j/2
    const float B = qij * fast_exp2((n - 1.0f) * fast_log2(r0)) * fast_rcp(n);
    const float dpow = fast_exp2(-0.5f * n * fast_log2(d2)); // d^-n without sqrt
    const float cpow = fast_exp2(-n * LOG2_CUT);             // 5^-n

    mol = __float_as_int(ai.w);
    return (d2 <= 25.0f) ? B * (dpow - cpow) : 0.0f;
}

// Vectorized edge kernel: 4 edges/thread; idx as int4, Rij as 3x float4.
__global__ void __launch_bounds__(BLOCK)
edge_kernel(const float4* __restrict__ atoms,
            const float* __restrict__ r0_table,
            const float4* __restrict__ Rij4,
            const int4* __restrict__ idx_i4,
            const int4* __restrict__ idx_j4,
            float* __restrict__ out, int nE) {
    constexpr float HALF_KE = 7.1998f; // 0.5 * 14.3996

    __shared__ float bins[NMOL];
    for (int t = threadIdx.x; t < NMOL; t += BLOCK) bins[t] = 0.0f;
    __syncthreads();

    const int nE4 = nE >> 2;
    const int stride = gridDim.x * BLOCK;
    for (int t = blockIdx.x * BLOCK + threadIdx.x; t < nE4; t += stride) {
        const int4 ii = idx_i4[t];
        const int4 jj = idx_j4[t];
        const float4 ra = Rij4[3 * t + 0];
        const float4 rb = Rij4[3 * t + 1];
        const float4 rc = Rij4[3 * t + 2];

        int m0, m1, m2, m3;
        const float p0 = edge_pot(atoms, r0_table, ii.x, jj.x, ra.x, ra.y, ra.z, m0);
        const float p1 = edge_pot(atoms, r0_table, ii.y, jj.y, ra.w, rb.x, rb.y, m1);
        const float p2 = edge_pot(atoms, r0_table, ii.z, jj.z, rb.z, rb.w, rc.x, m2);
        const float p3 = edge_pot(atoms, r0_table, ii.w, jj.w, rc.y, rc.z, rc.w, m3);

        if (p0 != 0.0f) atomicAdd(&bins[m0], p0);
        if (p1 != 0.0f) atomicAdd(&bins[m1], p1);
        if (p2 != 0.0f) atomicAdd(&bins[m2], p2);
        if (p3 != 0.0f) atomicAdd(&bins[m3], p3);
    }

    // Scalar tail for nE % 4 (empty for the canonical 6.4M edges).
    const int tail_start = nE4 << 2;
    const int* idx_i = (const int*)idx_i4;
    const int* idx_j = (const int*)idx_j4;
    const float* Rij = (const float*)Rij4;
    for (int e = tail_start + blockIdx.x * BLOCK + threadIdx.x; e < nE; e += stride) {
        int m;
        const float p = edge_pot(atoms, r0_table, idx_i[e], idx_j[e],
                                 Rij[3 * e + 0], Rij[3 * e + 1], Rij[3 * e + 2], m);
        if (p != 0.0f) atomicAdd(&bins[m], p);
    }

    __syncthreads();
    for (int t = threadIdx.x; t < NMOL; t += BLOCK) {
        const float v = bins[t];
        if (v != 0.0f) atomicAdd(&out[t], v * HALF_KE);
    }
}

// Fallback when d_ws can't hold the packed atoms: raw gathers (slower, correct).
__global__ void __launch_bounds__(BLOCK)
edge_kernel_raw(const float* __restrict__ q,
                const int* __restrict__ Z,
                const float* __restrict__ ns,
                const int* __restrict__ idx_m,
                const int* __restrict__ is_film,
                const float* __restrict__ r0_table,
                const float* __restrict__ Rij,
                const int* __restrict__ idx_i,
                const int* __restrict__ idx_j,
                float* __restrict__ out, int nE) {
    constexpr float HALF_KE = 7.1998f;
    constexpr float LOG2_CUT = 2.321928094887362f;

    __shared__ float bins[NMOL];
    for (int t = threadIdx.x; t < NMOL; t += BLOCK) bins[t] = 0.0f;
    __syncthreads();

    const int stride = gridDim.x * BLOCK;
    for (int e = blockIdx.x * BLOCK + threadIdx.x; e < nE; e += stride) {
        const int i = idx_i[e];
        const int j = idx_j[e];
        const float x = Rij[3 * e + 0];
        const float y = Rij[3 * e + 1];
        const float z = Rij[3 * e + 2];
        const float d2 = fmaf(x, x, fmaf(y, y, z * z));

        const float r0 = r0_table[((is_film[i] * 2 + is_film[j]) * ZMAX + Z[i]) * ZMAX + Z[j]];
        const float qij = fabsf(q[i] * q[j]);
        const float n = fmaf(0.5f, ns[j], ns[i]);
        const float B = qij * fast_exp2((n - 1.0f) * fast_log2(r0)) * fast_rcp(n);
        const float dpow = fast_exp2(-0.5f * n * fast_log2(d2));
        const float cpow = fast_exp2(-n * LOG2_CUT);

        if (d2 <= 25.0f) {
            atomicAdd(&bins[idx_m[i]], B * (dpow - cpow));
        }
    }

    __syncthreads();
    for (int t = threadIdx.x; t < NMOL; t += BLOCK) {
        const float v = bins[t];
        if (v != 0.0f) atomicAdd(&out[t], v * HALF_KE);
    }
}

__global__ void zero_out_kernel(float* __restrict__ out) {
    if (threadIdx.x < NMOL) out[threadIdx.x] = 0.0f;
}

extern "C" void kernel_launch(void* const* d_in, const int* in_sizes, int n_in,
                              void* d_out, int out_size, void* d_ws, size_t ws_size,
                              hipStream_t stream) {
    const float* q        = (const float*)d_in[0];
    const int*   Z        = (const int*)  d_in[1];
    const float* ns       = (const float*)d_in[2];
    const int*   idx_m    = (const int*)  d_in[3];
    const float* Rij      = (const float*)d_in[4];
    const int*   idx_i    = (const int*)  d_in[5];
    const int*   idx_j    = (const int*)  d_in[6];
    const int*   is_film  = (const int*)  d_in[7];
    const float* r0_table = (const float*)d_in[8];

    const int nA = in_sizes[0];
    const int nE = in_sizes[5];
    float* out = (float*)d_out;

    const size_t atoms_bytes = (size_t)nA * sizeof(float4);
    const int edge_grid = 2048;

    if (ws_size >= atoms_bytes) {
        float4* atoms = (float4*)d_ws;
        const int pack_grid = (nA + BLOCK - 1) / BLOCK;
        pack_atoms_kernel<<<pack_grid, BLOCK, 0, stream>>>(q, Z, ns, idx_m, is_film,
                                                           atoms, out, nA);
        edge_kernel<<<edge_grid, BLOCK, 0, stream>>>(atoms, r0_table,
                                                     (const float4*)Rij,
                                                     (const int4*)idx_i,
                                                     (const int4*)idx_j,
                                                     out, nE);
    } else {
        zero_out_kernel<<<1, BLOCK, 0, stream>>>(out);
        edge_kernel_raw<<<edge_grid, BLOCK, 0, stream>>>(q, Z, ns, idx_m, is_film, r0_table,
                                                         Rij, idx_i, idx_j, out, nE);
    }
}